// Round 8
// baseline (933.379 us; speedup 1.0000x reference)
//
#include <hip/hip_runtime.h>
#include <hip/hip_bf16.h>
#include <math.h>

// Problem constants
#define Bsz 256
#define Hh 26
#define Ww 26
#define Ll 624
#define DDc 128
#define CHc 256
#define NLl 4
#define NPIX (Hh * Ww)            // 676
#define NROWS (Bsz * NPIX)        // 173056
#define GRID_ELEMS (NROWS * DDc)  // 22151168
#define PBLK 11                   // 64-px blocks per batch image (11*64 = 704 >= 676)

typedef short short8v __attribute__((ext_vector_type(8)));   // 8 bf16 (4 VGPRs)
typedef float f32x4 __attribute__((ext_vector_type(4)));
typedef unsigned short ushort4v __attribute__((ext_vector_type(4)));

__device__ __forceinline__ unsigned short f2bf(float f) {
    union { float f; unsigned int u; } v; v.f = f;
    unsigned int u = v.u;
    return (unsigned short)((u + 0x7FFFu + ((u >> 16) & 1u)) >> 16);   // RNE
}

// Branchless gelu via Abramowitz-Stegun 7.1.26 erf (|err| < 1.5e-7)
__device__ __forceinline__ float fast_gelu(float x) {
    float z = x * 0.70710678118654752f;
    float a = fabsf(z);
    float t = 1.0f / fmaf(0.3275911f, a, 1.0f);
    float p = fmaf(1.061405429f, t, -1.453152027f);
    p = fmaf(p, t, 1.421413741f);
    p = fmaf(p, t, -0.284496736f);
    p = fmaf(p, t, 0.254829592f);
    float e = __expf(-a * a);
    float y = fmaf(-p * t, e, 1.0f);
    float er = copysignf(y, z);
    return 0.5f * x * (1.0f + er);
}

// ---------------------------------------------------------------------------
__global__ void build_inv_kernel(const int* __restrict__ coords, int* __restrict__ inv) {
    int i = threadIdx.x;
    if (i < NPIX) inv[i] = -1;
    __syncthreads();
    if (i < Ll) {
        int r = coords[2 * i + 0];
        int c = coords[2 * i + 1];
        inv[r * Ww + c] = i;
    }
}

// ---------------------------------------------------------------------------
__global__ __launch_bounds__(256) void scatter_kernel(const float* __restrict__ X,
                                                      const float* __restrict__ P,
                                                      const int* __restrict__ inv,
                                                      float* __restrict__ Y) {
    int idx = blockIdx.x * blockDim.x + threadIdx.x;
    int r = idx >> 5;
    int c4 = idx & 31;
    int b = r / NPIX;
    int pos = r - b * NPIX;
    int li = inv[pos];
    float4 v;
    if (li >= 0) v = *(const float4*)(X + ((size_t)(b * Ll + li) * DDc + c4 * 4));
    else         v = *(const float4*)(P + c4 * 4);
    *(float4*)(Y + ((size_t)r * DDc + c4 * 4)) = v;
}

// ---------------------------------------------------------------------------
// Pack w3 into MFMA-fragment order:
//   chunk g = ((l*9 + tap)*16 + nt)*4 + ks ; within chunk [lane(64)][8 bf16]:
//   n = nt*16 + (lane&15), k = ks*32 + (lane>>4)*8 + e.
__global__ __launch_bounds__(256) void pack3_kernel(const float* __restrict__ w3,
                                                    unsigned short* __restrict__ w3f) {
    int g = blockIdx.x * 4 + (threadIdx.x >> 6);
    int lane = threadIdx.x & 63;
    int ks = g & 3;
    int nt = (g >> 2) & 15;
    int lt = g >> 6;          // l*9 + tap
    int al = lane & 15, ah = lane >> 4;
    int n = nt * 16 + al;
    int k0 = ks * 32 + ah * 8;
    const float* src = w3 + ((size_t)lt * 128 + k0) * 256 + n;
    unsigned short* dst = w3f + ((size_t)g * 64 + lane) * 8;
#pragma unroll
    for (int e = 0; e < 8; ++e)
        dst[e] = f2bf(src[(size_t)e * 256]);
}

// pack w1: g = ((l*8 + nt)*8 + ks) ; d = nt*16+al, ch = ks*32+ah*8+e
__global__ __launch_bounds__(256) void pack1_kernel(const float* __restrict__ w1,
                                                    unsigned short* __restrict__ w1f) {
    int g = blockIdx.x * 4 + (threadIdx.x >> 6);
    int lane = threadIdx.x & 63;
    int ks = g & 7;
    int nt = (g >> 3) & 7;
    int l = g >> 6;
    int al = lane & 15, ah = lane >> 4;
    int d = nt * 16 + al;
    int c0 = ks * 32 + ah * 8;
    const float* src = w1 + ((size_t)l * 256 + c0) * 128 + d;
    unsigned short* dst = w1f + ((size_t)g * 64 + lane) * 8;
#pragma unroll
    for (int e = 0; e < 8; ++e)
        dst[e] = f2bf(src[(size_t)e * 128]);
}

// ---------------------------------------------------------------------------
__global__ __launch_bounds__(256) void ln_kernel(const float* __restrict__ Y,
                                                 const float* __restrict__ scale,
                                                 const float* __restrict__ bias,
                                                 unsigned short* __restrict__ Yn) {
    int wave = threadIdx.x >> 6;
    int lane = threadIdx.x & 63;
    int r = blockIdx.x * 4 + wave;
    const float* yr = Y + (size_t)r * DDc;
    float2 v = *(const float2*)(yr + lane * 2);
    float s = v.x + v.y;
#pragma unroll
    for (int off = 32; off >= 1; off >>= 1) s += __shfl_xor(s, off, 64);
    float mean = s * (1.0f / 128.0f);
    float dx = v.x - mean, dy = v.y - mean;
    float s2 = dx * dx + dy * dy;
#pragma unroll
    for (int off = 32; off >= 1; off >>= 1) s2 += __shfl_xor(s2, off, 64);
    float rstd = rsqrtf(s2 * (1.0f / 128.0f) + 1e-5f);
    float2 sc = *(const float2*)(scale + lane * 2);
    float2 bi = *(const float2*)(bias + lane * 2);
    ushort2 o;
    o.x = f2bf(dx * rstd * sc.x + bi.x);
    o.y = f2bf(dy * rstd * sc.y + bi.y);
    *(ushort2*)(Yn + (size_t)r * DDc + lane * 2) = o;
}

// ---------------------------------------------------------------------------
// Fused MFMA layer kernel, v2: block = (b, 64-contiguous-pixel tile).
// 512 threads = 8 waves. Wave wv owns conv N-cols [wv*32, wv*32+32) (2 n-tiles)
// and 1x1 d-cols [wv*16, wv*16+16) (1 tile). Small per-wave acc (32+16 AGPR)
// -> 4 waves/SIMD occupancy. A-slab = 6 rows x 28 cols x 128ch bf16 (43008 B),
// ALIASED with H [64 m][256 n] bf16 (32768 B); +256 B zero pad.
#define Z_OFF 43008
#define LDS_TOTAL 43264

__global__ __launch_bounds__(512, 4) void conv_mfma_kernel(
    const unsigned short* __restrict__ Yn,
    const unsigned short* __restrict__ w3f,    // fragment-packed, per layer
    const float* __restrict__ b3l,
    const unsigned short* __restrict__ w1f,    // fragment-packed, per layer
    const float* __restrict__ b1l,
    float* __restrict__ Y) {
    __shared__ __align__(16) char lds[LDS_TOTAL];

    int bx = blockIdx.x;
    int b = bx / PBLK;
    int p0 = (bx - b * PBLK) * 64;            // first pixel of this tile
    int r0 = (p0 * 2521) >> 16;               // p0/26
    int tid = threadIdx.x;
    int lane = tid & 63, wv = tid >> 6;
    int al = lane & 15, ah = lane >> 4;

    // ---- stage A: rows r0-1 .. r0+4, cols -1..26, 128ch bf16, XOR-swizzled
    for (int i = tid; i < 6 * 28 * 16; i += 512) {     // 16B chunks
        int row6 = i / (28 * 16);
        int rem = i - row6 * (28 * 16);
        int col = rem >> 4;
        int c8 = (rem & 15) << 3;
        int hs = r0 - 1 + row6;
        int ws = col - 1;
        uint4 v = make_uint4(0u, 0u, 0u, 0u);
        if (hs >= 0 && hs < Hh && ws >= 0 && ws < Ww)
            v = *(const uint4*)(Yn + (((size_t)(b * Hh + hs) * Ww + ws) << 7) + c8);
        int r = row6 * 28 + col;
        unsigned int addr = (unsigned int)(r * 256 + c8 * 2);
        addr ^= (unsigned int)((r & 7) << 4);
        *(uint4*)(lds + addr) = v;
    }
    if (tid < 16) *(uint4*)(lds + Z_OFF + tid * 16) = make_uint4(0u, 0u, 0u, 0u);
    __syncthreads();

    // ---- per-lane M decomposition (pixel p = p0 + mt*16 + al)
    int r00[4]; bool mpad[4];
#pragma unroll
    for (int mt = 0; mt < 4; ++mt) {
        int p = p0 + mt * 16 + al;
        bool pad = (p >= NPIX);
        int rh = (p * 2521) >> 16;            // p/26
        int w = p - rh * 26;
        int srow = rh - r0;                   // 0..3
        if (pad) { srow = 0; w = 0; }
        mpad[mt] = pad;
        r00[mt] = srow * 28 + w;
    }

    // ---- conv 3x3 via swapped MFMA, software-pipelined depth 1 (pinned)
    f32x4 acc[4][2];
#pragma unroll
    for (int mt = 0; mt < 4; ++mt) { acc[mt][0] = (f32x4)0.0f; acc[mt][1] = (f32x4)0.0f; }

    // wave wv owns nt chunks {2wv, 2wv+1}: chunk = 512 shorts; nt stride = 4 chunks
    const unsigned short* pB = w3f + wv * 4096 + lane * 8;
    const unsigned short* pBt = pB;

    unsigned int ah16 = (unsigned int)(ah * 16);
    unsigned int abase[4];
#pragma unroll
    for (int mt = 0; mt < 4; ++mt) {
        int row = r00[mt];                    // tap 0
        unsigned int sw = (unsigned int)((row & 7) << 4);
        abase[mt] = mpad[mt] ? (unsigned int)(Z_OFF) + ah16
                             : ((unsigned int)(row << 8) + (ah16 ^ sw));
    }

    short8v bc[2], afc[4];
#pragma unroll
    for (int g = 0; g < 2; ++g) bc[g] = *(const short8v*)(pBt + g * 2048);
#pragma unroll
    for (int mt = 0; mt < 4; ++mt) afc[mt] = *(const short8v*)(lds + abase[mt]);

    int dh = 0, dw = 0;
#pragma unroll 1
    for (int tap = 0; tap < 9; ++tap) {
        int dwn = dw + 1, dhn = dh;
        if (dwn == 3) { dwn = 0; dhn += 1; }
        unsigned int abasen[4];
#pragma unroll
        for (int mt = 0; mt < 4; ++mt) {
            int row = r00[mt] + dhn * 28 + dwn;
            if (row > 167) row = 167;         // tap==8 dummy prefetch clamp
            unsigned int sw = (unsigned int)((row & 7) << 4);
            abasen[mt] = mpad[mt] ? (unsigned int)(Z_OFF) + ah16
                                  : ((unsigned int)(row << 8) + (ah16 ^ sw));
        }
#pragma unroll
        for (int ks = 0; ks < 4; ++ks) {
            short8v bn[2], afn[4];
            const unsigned short* pn = (ks < 3) ? (pBt + (ks + 1) * 512) : (pBt + 32768);
#pragma unroll
            for (int g = 0; g < 2; ++g) bn[g] = *(const short8v*)(pn + g * 2048);
#pragma unroll
            for (int mt = 0; mt < 4; ++mt) {
                unsigned int a = (ks < 3) ? (abase[mt] ^ (unsigned int)((ks + 1) << 6))
                                          : abasen[mt];
                afn[mt] = *(const short8v*)(lds + a);
            }
            // Pin: next-step loads issue BEFORE this step's MFMA cluster.
            __builtin_amdgcn_sched_barrier(0);
#pragma unroll
            for (int mt = 0; mt < 4; ++mt)
#pragma unroll
                for (int g = 0; g < 2; ++g)
                    acc[mt][g] = __builtin_amdgcn_mfma_f32_16x16x32_bf16(
                        bc[g], afc[mt], acc[mt][g], 0, 0, 0);
#pragma unroll
            for (int g = 0; g < 2; ++g) bc[g] = bn[g];
#pragma unroll
            for (int mt = 0; mt < 4; ++mt) afc[mt] = afn[mt];
        }
#pragma unroll
        for (int mt = 0; mt < 4; ++mt) abase[mt] = abasen[mt];
        pBt += 32768;
        dw = dwn; dh = dhn;
    }
    __syncthreads();   // all A-reads done; H region may now overwrite A region

    // ---- bias + gelu -> H [64 m][256 n] bf16, packed b64 writes
    unsigned int hswz = ((unsigned int)(al & 7)) << 4;   // m&7 == al&7
#pragma unroll
    for (int g = 0; g < 2; ++g) {
        int n0 = wv * 32 + g * 16 + ah * 4;
        float4 bv = *(const float4*)(b3l + n0);
#pragma unroll
        for (int mt = 0; mt < 4; ++mt) {
            int m = mt * 16 + al;
            ushort4v o;
            o[0] = f2bf(fast_gelu(acc[mt][g][0] + bv.x));
            o[1] = f2bf(fast_gelu(acc[mt][g][1] + bv.y));
            o[2] = f2bf(fast_gelu(acc[mt][g][2] + bv.z));
            o[3] = f2bf(fast_gelu(acc[mt][g][3] + bv.w));
            unsigned int addr = ((unsigned int)(m * 512 + n0 * 2)) ^ hswz;
            *(ushort4v*)(lds + addr) = o;
        }
    }
    __syncthreads();

    // ---- 1x1 via MFMA: [64 x 256] @ [256 -> 128]; wave wv owns d-cols wv*16..+16
    f32x4 acc1[4];
#pragma unroll
    for (int mt = 0; mt < 4; ++mt) acc1[mt] = (f32x4)0.0f;
    const unsigned short* pW1 = w1f + wv * 4096 + lane * 8;

#pragma unroll
    for (int ks = 0; ks < 8; ++ks) {
        short8v hf[4], wf;
#pragma unroll
        for (int mt = 0; mt < 4; ++mt) {
            unsigned int a = ((unsigned int)((mt * 16 + al) * 512 + ks * 64 + ah * 16)) ^ hswz;
            hf[mt] = *(const short8v*)(lds + a);
        }
        wf = *(const short8v*)(pW1 + ks * 512);
#pragma unroll
        for (int mt = 0; mt < 4; ++mt)
            acc1[mt] = __builtin_amdgcn_mfma_f32_16x16x32_bf16(hf[mt], wf, acc1[mt], 0, 0, 0);
    }

    // ---- bias + residual into Y (fp32); C layout: d = wv*16+al, m = mt*16+ah*4+j
    {
        int d = wv * 16 + al;
        float bias = b1l[d];
#pragma unroll
        for (int mt = 0; mt < 4; ++mt) {
#pragma unroll
            for (int j = 0; j < 4; ++j) {
                int p = p0 + mt * 16 + ah * 4 + j;
                if (p < NPIX) {
                    float* yp = Y + (((size_t)(b * NPIX + p)) << 7) + d;
                    *yp += acc1[mt][j] + bias;
                }
            }
        }
    }
}

// ---------------------------------------------------------------------------
__global__ __launch_bounds__(256) void gather_kernel(const float* __restrict__ Y,
                                                     const int* __restrict__ coords,
                                                     float* __restrict__ Z) {
    int idx = blockIdx.x * blockDim.x + threadIdx.x;
    int r = idx >> 5;
    int c4 = idx & 31;
    int b = r / Ll;
    int li = r - b * Ll;
    int row = coords[2 * li + 0];
    int col = coords[2 * li + 1];
    float4 v = *(const float4*)(Y + (((size_t)(b * NPIX + row * Ww + col)) * DDc + c4 * 4));
    *(float4*)(Z + ((size_t)r * DDc + c4 * 4)) = v;
}

// ---------------------------------------------------------------------------
extern "C" void kernel_launch(void* const* d_in, const int* in_sizes, int n_in,
                              void* d_out, int out_size, void* d_ws, size_t ws_size,
                              hipStream_t stream) {
    const float* X = (const float*)d_in[0];
    const int* coords = (const int*)d_in[1];
    const float* P = (const float*)d_in[2];
    const float* ln_scale = (const float*)d_in[3];
    const float* ln_bias = (const float*)d_in[4];
    const float* w3 = (const float*)d_in[5];
    const float* b3 = (const float*)d_in[6];
    const float* w1 = (const float*)d_in[7];
    const float* b1 = (const float*)d_in[8];

    float* Y = (float*)d_ws;
    unsigned short* Yn = (unsigned short*)(Y + GRID_ELEMS);
    unsigned short* w3f = Yn + GRID_ELEMS;                       // 4*9*32768
    unsigned short* w1f = w3f + (size_t)NLl * 9 * CHc * DDc;     // 4*32768
    int* inv = (int*)(w1f + (size_t)NLl * DDc * CHc);

    build_inv_kernel<<<1, 1024, 0, stream>>>(coords, inv);

    pack3_kernel<<<(NLl * 9 * 16 * 4) / 4, 256, 0, stream>>>(w3, w3f);
    pack1_kernel<<<(NLl * 8 * 8) / 4, 256, 0, stream>>>(w1, w1f);

    scatter_kernel<<<(NROWS * 32) / 256, 256, 0, stream>>>(X, P, inv, Y);

    for (int l = 0; l < NLl; ++l) {
        ln_kernel<<<NROWS / 4, 256, 0, stream>>>(Y, ln_scale + l * DDc, ln_bias + l * DDc, Yn);
        conv_mfma_kernel<<<Bsz * PBLK, 512, 0, stream>>>(
            Yn,
            w3f + (size_t)l * 9 * CHc * DDc,
            b3 + (size_t)l * CHc,
            w1f + (size_t)l * DDc * CHc,
            b1 + (size_t)l * DDc,
            Y);
    }

    gather_kernel<<<(Bsz * Ll * 32) / 256, 256, 0, stream>>>(Y, coords, (float*)d_out);
}